// Round 7
// baseline (450.960 us; speedup 1.0000x reference)
//
#include <hip/hip_runtime.h>
#include <hip/hip_bf16.h>
#include <math.h>

// Problem constants (fixed by the reference module)
#define BB 8
#define QQ 900
#define EE 256
#define NH 8
#define NL 4
#define NP 4
#define HD 32
#define SS 19560   // sum of H*W over levels

typedef short short8 __attribute__((ext_vector_type(8)));
typedef float f32x4 __attribute__((ext_vector_type(4)));

__device__ __forceinline__ unsigned short f2bf(float f) {
    __hip_bfloat16 h = __float2bfloat16(f);
    return *reinterpret_cast<unsigned short*>(&h);
}

__device__ __forceinline__ short8 cvt8(const float4 a, const float4 b) {
    unsigned short tmp[8];
    tmp[0] = f2bf(a.x); tmp[1] = f2bf(a.y); tmp[2] = f2bf(a.z); tmp[3] = f2bf(a.w);
    tmp[4] = f2bf(b.x); tmp[5] = f2bf(b.y); tmp[6] = f2bf(b.z); tmp[7] = f2bf(b.w);
    return *(const short8*)tmp;
}

// ---------------------------------------------------------------------------
// Pack all weights into bf16 MFMA B-fragment order. Fragment f within a
// region: cb = f>>5 (64-col block), ks = (f>>2)&7 (32-k slice), nt = f&3
// (16-col tile). Lane ln holds B[k = ks*32+(ln>>4)*8+j][col = cb*64+nt*16+(ln&15)].
// Regions: [0..8192) W_v(N=256), [8192..20480) W_off||W_attn (N=384),
// [20480..28672) W_out (N=256).
// ---------------------------------------------------------------------------
__global__ __launch_bounds__(256) void pack_all(
    const float* __restrict__ Wv, const float* __restrict__ Woff,
    const float* __restrict__ Wattn, const float* __restrict__ Wout,
    unsigned short* __restrict__ Wp)
{
    const int tid = blockIdx.x * 256 + threadIdx.x;  // 0..28671
    const float* src = Wv;
    int srcN = 256;
    int u = tid;
    if (tid >= 20480)     { u = tid - 20480; src = Wout; srcN = 256; }
    else if (tid >= 8192) { u = tid - 8192; }

    const int f = u >> 6, ln2 = u & 63;
    const int cb = f >> 5, ks = (f >> 2) & 7, nt = f & 3;
    int ncol = cb * 64 + nt * 16 + (ln2 & 15);
    if (tid >= 8192 && tid < 20480) {
        if (ncol < 256) { src = Woff; srcN = 256; }
        else            { src = Wattn; srcN = 128; ncol -= 256; }
    }
    const int k0 = ks * 32 + (ln2 >> 4) * 8;
    unsigned short tmp[8];
#pragma unroll
    for (int j = 0; j < 8; ++j)
        tmp[j] = f2bf(src[(size_t)(k0 + j) * srcN + ncol]);
    *(short8*)(Wp + (size_t)tid * 8) = *(const short8*)tmp;
}

// ---------------------------------------------------------------------------
// Value projection: wave = 16 rows x 256 cols, block = 4 waves = 64 rows.
// No LDS/barriers. Depth-2 register double-buffer on the A stream (the only
// HBM-latency-critical path) -> 2 KB in flight per wave; acc[16]=64 regs so
// ~4 waves/SIMD hide the rest. All acc indexing static (R3/R4 scratch lesson).
// ---------------------------------------------------------------------------
__global__ __launch_bounds__(256) void gemm_v_bf16(
    const float* __restrict__ A, const unsigned short* __restrict__ Wp,
    const float* __restrict__ bias, unsigned short* __restrict__ C, int M)
{
    const int t = threadIdx.x;
    const int w = t >> 6, ln = t & 63, quad = ln >> 4, m16 = ln & 15;
    const int row0 = blockIdx.x * 64 + w * 16;   // wave's 16-row strip
    const int r0 = row0 + m16;
    const bool valid = r0 < M;

    const float* ap = A + (size_t)r0 * 256 + quad * 8;
    const float4 fz = make_float4(0.f, 0.f, 0.f, 0.f);

    f32x4 acc[16] = {};
    float4 pa[2][2];

    pa[0][0] = valid ? *(const float4*)(ap)      : fz;
    pa[0][1] = valid ? *(const float4*)(ap + 4)  : fz;
    pa[1][0] = valid ? *(const float4*)(ap + 32) : fz;
    pa[1][1] = valid ? *(const float4*)(ap + 36) : fz;

#pragma unroll
    for (int ks = 0; ks < 8; ++ks) {
        const int buf = ks & 1;
        const short8 af = cvt8(pa[buf][0], pa[buf][1]);
        if (ks + 2 < 8) {
            const float* p = ap + (ks + 2) * 32;
            pa[buf][0] = valid ? *(const float4*)p       : fz;
            pa[buf][1] = valid ? *(const float4*)(p + 4) : fz;
        }
#pragma unroll
        for (int nt = 0; nt < 16; ++nt) {
            const int fidx = ((nt >> 2) * 8 + ks) * 4 + (nt & 3);
            const short8 bf = *(const short8*)(Wp + ((size_t)fidx * 64 + ln) * 8);
            acc[nt] = __builtin_amdgcn_mfma_f32_16x16x32_bf16(af, bf, acc[nt], 0, 0, 0);
        }
    }

    // epilogue: + bias, bf16 row-major [M,256] (proven store pattern)
    float bset[16];
#pragma unroll
    for (int nt = 0; nt < 16; ++nt) bset[nt] = bias[(nt >> 2) * 64 + (nt & 3) * 16 + m16];

#pragma unroll
    for (int r = 0; r < 4; ++r) {
        const int row = row0 + quad * 4 + r;
        if (row >= M) continue;
        unsigned short* crow = C + (size_t)row * 256 + m16;
#pragma unroll
        for (int nt = 0; nt < 16; ++nt)
            crow[(nt >> 2) * 64 + (nt & 3) * 16] = f2bf(acc[nt][r] + bset[nt]);
    }
}

// ---------------------------------------------------------------------------
// Query-side MFMA GEMM: wave = 16 rows x 64 cols, block = 64 rows x 64 cols.
// Same depth-2 A prefetch. C fp32 = A @ W + bias (+ res).
// ---------------------------------------------------------------------------
__global__ __launch_bounds__(256) void gemm_q(
    const float* __restrict__ A, const unsigned short* __restrict__ Wp,
    const float* __restrict__ bias0, const float* __restrict__ bias1, int split,
    const float* __restrict__ res, float* __restrict__ C, int M, int N)
{
    const int t = threadIdx.x;
    const int w = t >> 6, ln = t & 63, quad = ln >> 4, m16 = ln & 15;
    const int cb = blockIdx.x;
    const int row0 = blockIdx.y * 64 + w * 16;
    const int r0 = row0 + m16;
    const bool valid = r0 < M;

    const float* ap = A + (size_t)r0 * 256 + quad * 8;
    const float4 fz = make_float4(0.f, 0.f, 0.f, 0.f);

    f32x4 acc[4] = {};
    float4 pa[2][2];

    pa[0][0] = valid ? *(const float4*)(ap)      : fz;
    pa[0][1] = valid ? *(const float4*)(ap + 4)  : fz;
    pa[1][0] = valid ? *(const float4*)(ap + 32) : fz;
    pa[1][1] = valid ? *(const float4*)(ap + 36) : fz;

#pragma unroll
    for (int ks = 0; ks < 8; ++ks) {
        const int buf = ks & 1;
        const short8 af = cvt8(pa[buf][0], pa[buf][1]);
        if (ks + 2 < 8) {
            const float* p = ap + (ks + 2) * 32;
            pa[buf][0] = valid ? *(const float4*)p       : fz;
            pa[buf][1] = valid ? *(const float4*)(p + 4) : fz;
        }
#pragma unroll
        for (int nt = 0; nt < 4; ++nt) {
            const short8 bf = *(const short8*)(Wp + ((size_t)((cb * 8 + ks) * 4 + nt) * 64 + ln) * 8);
            acc[nt] = __builtin_amdgcn_mfma_f32_16x16x32_bf16(af, bf, acc[nt], 0, 0, 0);
        }
    }

#pragma unroll
    for (int nt = 0; nt < 4; ++nt) {
        const int col = cb * 64 + nt * 16 + m16;
        const float bv = (col < split) ? bias0[col] : bias1[col - split];
#pragma unroll
        for (int r = 0; r < 4; ++r) {
            const int row = row0 + quad * 4 + r;
            if (row >= M) continue;
            float o = acc[nt][r] + bv;
            if (res) o += res[(size_t)row * N + col];
            C[(size_t)row * N + col] = o;
        }
    }
}

// ---------------------------------------------------------------------------
// Sampling: precompute per-(h,l,p) tuples (clamped addresses + weights with
// validity folded in) in LDS, then a tight unconditional gather loop.
// 256 threads = 2 queries; per query 8 heads x 16 lanes, 2 ch/lane.
// ---------------------------------------------------------------------------
__global__ __launch_bounds__(256) void msda_sample2(
    const unsigned short* __restrict__ v,   // [B*S, 256] bf16
    const float* __restrict__ qcat,         // [B*Q, 384]: off 0..255, logits 256..383
    const float* __restrict__ refp,         // [B*Q, 8]
    float* __restrict__ out)                // [B*Q, 256]
{
    const int t = threadIdx.x;
    const int tq = t >> 7, tt = t & 127;
    const int bq = blockIdx.x * 2 + tq;
    const int b = bq / QQ;

    __shared__ float s_off[2][256];
    __shared__ float s_log[2][128];
    __shared__ float s_ref[2][8];
    __shared__ int   s_adr[2][8][17][4];   // [q][head][lp + pad][corner]
    __shared__ float s_wt [2][8][17][4];

    const float* qrow = qcat + (size_t)bq * 384;
    *(float2*)&s_off[tq][tt * 2] = *(const float2*)(qrow + tt * 2);
    s_log[tq][tt] = qrow[256 + tt];
    if (tt < 8) s_ref[tq][tt] = refp[(size_t)bq * 8 + tt];
    __syncthreads();

    {   // precompute: this thread owns tuple (head hh, level pl, point pp)
        const int hh = tt >> 4, lp = tt & 15, pl = lp >> 2, pp = lp & 3;
        const int Wl = 160 >> pl;
        const int Hl = (pl == 0) ? 92 : (pl == 1) ? 46 : (pl == 2) ? 23 : 12;
        const int st = (pl == 0) ? 0 : (pl == 1) ? 14720 : (pl == 2) ? 18400 : 19320;

        const float* lg = &s_log[tq][hh * 16];
        float m = lg[0];
#pragma unroll
        for (int i = 1; i < 16; ++i) m = fmaxf(m, lg[i]);
        float ssum = 0.f;
#pragma unroll
        for (int i = 0; i < 16; ++i) ssum += __expf(lg[i] - m);
        const float wt = __expf(lg[lp] - m) / ssum;

        const float rx = s_ref[tq][pl * 2 + 0];
        const float ry = s_ref[tq][pl * 2 + 1];
        const float ox = s_off[tq][hh * 32 + pl * 8 + pp * 2 + 0];
        const float oy = s_off[tq][hh * 32 + pl * 8 + pp * 2 + 1];
        const float x = fmaf(rx, (float)Wl, ox) - 0.5f;
        const float y = fmaf(ry, (float)Hl, oy) - 0.5f;
        const float xf = floorf(x), yf = floorf(y);
        const int x0 = (int)xf, y0 = (int)yf;
        const float wx = x - xf, wy = y - yf;

        const float fx0 = (x0 >= 0 && x0 < Wl) ? 1.f : 0.f;
        const float fx1 = (x0 + 1 >= 0 && x0 + 1 < Wl) ? 1.f : 0.f;
        const float fy0 = (y0 >= 0 && y0 < Hl) ? 1.f : 0.f;
        const float fy1 = (y0 + 1 >= 0 && y0 + 1 < Hl) ? 1.f : 0.f;
        const int x0c = min(max(x0, 0), Wl - 1);
        const int x1c = min(max(x0 + 1, 0), Wl - 1);
        const int y0c = min(max(y0, 0), Hl - 1);
        const int y1c = min(max(y0 + 1, 0), Hl - 1);

        s_adr[tq][hh][lp][0] = st + y0c * Wl + x0c;
        s_adr[tq][hh][lp][1] = st + y0c * Wl + x1c;
        s_adr[tq][hh][lp][2] = st + y1c * Wl + x0c;
        s_adr[tq][hh][lp][3] = st + y1c * Wl + x1c;
        s_wt[tq][hh][lp][0] = wt * (1.f - wy) * (1.f - wx) * fy0 * fx0;
        s_wt[tq][hh][lp][1] = wt * (1.f - wy) * wx * fy0 * fx1;
        s_wt[tq][hh][lp][2] = wt * wy * (1.f - wx) * fy1 * fx0;
        s_wt[tq][hh][lp][3] = wt * wy * wx * fy1 * fx1;
    }
    __syncthreads();

    const int hh = tt >> 4, d2 = tt & 15;
    const unsigned short* vb = v + (size_t)b * SS * 256 + hh * 32 + d2 * 2;

    float ax0 = 0.f, ay0 = 0.f, ax1 = 0.f, ay1 = 0.f;
#pragma unroll
    for (int s = 0; s < 16; ++s) {
        const int4   rr = *(const int4*)&s_adr[tq][hh][s][0];
        const float4 ww = *(const float4*)&s_wt[tq][hh][s][0];
        const unsigned int u00 = *(const unsigned int*)(vb + (size_t)rr.x * 256);
        const unsigned int u01 = *(const unsigned int*)(vb + (size_t)rr.y * 256);
        const unsigned int u10 = *(const unsigned int*)(vb + (size_t)rr.z * 256);
        const unsigned int u11 = *(const unsigned int*)(vb + (size_t)rr.w * 256);
        ax0 = fmaf(ww.x, __uint_as_float(u00 << 16), ax0);
        ay0 = fmaf(ww.x, __uint_as_float(u00 & 0xffff0000u), ay0);
        ax0 = fmaf(ww.y, __uint_as_float(u01 << 16), ax0);
        ay0 = fmaf(ww.y, __uint_as_float(u01 & 0xffff0000u), ay0);
        ax1 = fmaf(ww.z, __uint_as_float(u10 << 16), ax1);
        ay1 = fmaf(ww.z, __uint_as_float(u10 & 0xffff0000u), ay1);
        ax1 = fmaf(ww.w, __uint_as_float(u11 << 16), ax1);
        ay1 = fmaf(ww.w, __uint_as_float(u11 & 0xffff0000u), ay1);
    }
    float2 o;
    o.x = ax0 + ax1;
    o.y = ay0 + ay1;
    *(float2*)(out + (size_t)bq * 256 + tt * 2) = o;
}

extern "C" void kernel_launch(void* const* d_in, const int* in_sizes, int n_in,
                              void* d_out, int out_size, void* d_ws, size_t ws_size,
                              hipStream_t stream) {
    const float* query  = (const float*)d_in[0];
    const float* value  = (const float*)d_in[1];
    const float* refp   = (const float*)d_in[2];
    const float* W_off  = (const float*)d_in[4];
    const float* b_off  = (const float*)d_in[5];
    const float* W_attn = (const float*)d_in[6];
    const float* b_attn = (const float*)d_in[7];
    const float* W_v    = (const float*)d_in[8];
    const float* b_v    = (const float*)d_in[9];
    const float* W_out  = (const float*)d_in[10];
    const float* b_out  = (const float*)d_in[11];
    float* out = (float*)d_out;

    // Workspace layout
    unsigned short* v_bf = (unsigned short*)d_ws;                 // B*S*256 bf16 = 80.1 MB
    unsigned short* wp   = v_bf + (size_t)BB * SS * 256;          // 28672*8 bf16 = 448 KB
    unsigned short* wp_v = wp;                                    // region 0
    unsigned short* wp_q = wp + (size_t)8192 * 8;                 // region 1 (N=384)
    unsigned short* wp_o = wp + (size_t)20480 * 8;                // region 2 (N=256)
    float* qcat_ws = (float*)(wp + (size_t)28672 * 8);            // B*Q*384 fp32 = 11 MB
    float* samp_ws = qcat_ws + (size_t)BB * QQ * 384;             // B*Q*256 fp32 = 7.4 MB

    const int Mv = BB * SS;   // 156480
    const int Mq = BB * QQ;   // 7200

    // 0. pack all weights into bf16 MFMA fragment order
    pack_all<<<dim3(112), dim3(256), 0, stream>>>(W_v, W_off, W_attn, W_out, wp);
    // 1. value projection (bf16 MFMA, barrier-free, depth-2 prefetch)
    gemm_v_bf16<<<dim3((Mv + 63) / 64), dim3(256), 0, stream>>>(
        value, wp_v, b_v, v_bf, Mv);
    // 2. fused offsets+logits: qcat = query @ [W_off||W_attn] + [b_off||b_attn]
    gemm_q<<<dim3(6, (Mq + 63) / 64), dim3(256), 0, stream>>>(
        query, wp_q, b_off, b_attn, 256, nullptr, qcat_ws, Mq, 384);
    // 3. softmax + bilinear sampling + weighted sum
    msda_sample2<<<dim3(Mq / 2), dim3(256), 0, stream>>>(v_bf, qcat_ws, refp, samp_ws);
    // 4. output projection + residual
    gemm_q<<<dim3(4, (Mq + 63) / 64), dim3(256), 0, stream>>>(
        samp_ws, wp_o, b_out, b_out, 1 << 30, query, out, Mq, 256);
}